// Round 6
// baseline (167.854 us; speedup 1.0000x reference)
//
#include <hip/hip_runtime.h>

// NCC loss, fused single pass. Layout [n][1][d][h][w], n=2, d=160, h=192, w=192, f32.
// R6: R5 structure (double-buffered global_load_lds staging, per-slice barrier) with
//   (1) staging re-based at wbase-2 (TROW=68): each thread's 8 needed cols are
//       16B-aligned -> 2x ds_read_b128 per row/array (20/step vs 30: R5's LDS pipe
//       was the busiest at ~61%).
//       W-edge repair (DMA lanes clamp OOB addresses; R4: DMA must never be masked):
//         left  (wbase=0,  tx=0):  fetched seg0 = cols[0..3] at local[-2..1] slots
//                                  -> a = [0,0,a0,a1,a4..a7]
//         right (wbase=128,tx=15): fetched seg16 = cols[188..191] at local[190..193]
//                                  -> a = [a0..a3, a6,a7, 0,0]
//   (2) running D-window sum Dsum += new - ring[p] (40 ops) instead of 5-slot
//       re-sum (100 ops); ring & Dsum zero-init.
//   Ring stays in registers: NO occupancy clamp (R3's (256,4) spilled -> 1.1 GB).

namespace {
constexpr int Wd = 192, Hd = 192, Dd = 160;
constexpr int SH = 192;              // h stride (floats)
constexpr int SD = 192 * 192;        // d stride
constexpr long SN = (long)SD * Dd;   // n stride
constexpr int CD = 6;                // d outputs per chunk; T = CD+4 = 10
constexpr int NCHUNK = 27;           // ceil(160/6)
constexpr int TROW = 68;             // LDS row stride (floats): 17 segs of 16B
constexpr int ROWS = 20;             // h rows staged (16 outputs + 4 halo)
constexpr int SEGA = 17 * ROWS;      // 340 segs per array
constexpr int TILEF = 2 * ROWS * TROW; // 2720 floats per buffer (10.88 KB)
constexpr float INV_V = 1.0f / 125.0f;
constexpr float EPSf = 1e-5f;

__device__ __forceinline__ void wslide(const float h[8], float o[4]) {
  float s0 = h[0] + h[1] + h[2] + h[3] + h[4];
  float s1 = s0 - h[0] + h[5];
  float s2 = s1 - h[1] + h[6];
  float s3 = s2 - h[2] + h[7];
  o[0] = s0; o[1] = s1; o[2] = s2; o[3] = s3;
}

__device__ __forceinline__ void gl_lds16(const float* g, float* l) {
  __builtin_amdgcn_global_load_lds(
      (const __attribute__((address_space(1))) void*)g,
      (__attribute__((address_space(3))) void*)l, 16, 0, 0);
}
} // namespace

__global__ __launch_bounds__(256) void ncc_fused(const float* __restrict__ I,
                                                 const float* __restrict__ Jv,
                                                 float* __restrict__ out) {
  __shared__ float tile[2][TILEF];   // 21.76 KB double buffer
  __shared__ float red[4];

  const int tid = threadIdx.x;
  const int tx = tid & 15;        // w-run index (4 outputs each)
  const int ty = tid >> 4;        // h row within 16-tall tile
  const int wbase = blockIdx.x * 64;
  const int hbase = blockIdx.y * 16;
  const int n  = blockIdx.z / NCHUNK;
  const int d_lo = (blockIdx.z % NCHUNK) * CD;

  const float* Ib = I  + (long)n * SN;
  const float* Jb = Jv + (long)n * SN;

  // ---- staging descriptors: 680 16B-segs; wave w owns segs [w*170,(w+1)*170) ----
  // waves 0,1 -> I (segs 0..339), waves 2,3 -> J. 170 = 2*64 + 42.
  const int wave = tid >> 6, lane = tid & 63;
  const float* gsrc = (wave >= 2) ? Jb : Ib;
  int goff[3]; int loff[3]; bool on[3];
  #pragma unroll
  for (int r = 0; r < 3; ++r) {
    const int seg = wave * 170 + r * 64 + lane;
    on[r] = (r < 2) || (lane < 42);               // lane 0 always active (DMA base!)
    const int rem = seg % SEGA;
    const int row = rem / 17, c16 = rem % 17;
    const int hh = hbase + row - 2;
    const int hc = min(max(hh, 0), Hd - 1);       // CLAMP, never mask
    const int gw = wbase - 2 + c16 * 4;
    const int gc = min(max(gw, 0), Wd - 4);
    goff[r] = hc * SH + gc;
    loff[r] = seg * 4;                            // float offset (seg*16 bytes)
  }

  // ---- stage slice d_lo-2 into buffer 0 ----
  {
    const int s0 = d_lo - 2;
    if (s0 >= 0 && s0 < Dd) {
      const float* base = gsrc + (long)s0 * SD;
      #pragma unroll
      for (int r = 0; r < 3; ++r) if (on[r]) gl_lds16(base + goff[r], &tile[0][loff[r]]);
    }
  }
  __syncthreads();

  // W-edge repair flags (see header comment)
  const bool zl = (wbase == 0)   && (tx == 0);
  const bool zr = (wbase == 128) && (tx == 15);

  float ring[5][5][4];   // [phase][channel:{I,J,II,JJ,IJ}][k]
  float Dsum[5][4];      // running D-window sums
  #pragma unroll
  for (int c = 0; c < 5; ++c) {
    #pragma unroll
    for (int k = 0; k < 4; ++k) {
      Dsum[c][k] = 0.f;
      #pragma unroll
      for (int q = 0; q < 5; ++q) ring[q][c][k] = 0.f;
    }
  }
  float acc = 0.0f;

  constexpr int T = CD + 4; // 10 steps; output d = d_lo + t - 4 for t>=4
  for (int t0 = 0; t0 < T; t0 += 5) {
    #pragma unroll
    for (int p = 0; p < 5; ++p) {             // phase = t % 5
      const int t = t0 + p;
      const int s = d_lo - 2 + t;             // slice in current buffer

      // ---- DMA slice s+1 into the other buffer (overlaps this step's compute) ----
      {
        const int sn = s + 1;
        if ((t + 1) < T && sn >= 0 && sn < Dd) {   // wave-uniform condition
          const float* base = gsrc + (long)sn * SD;
          float* dst = &tile[(t + 1) & 1][0];
          #pragma unroll
          for (int r = 0; r < 3; ++r) if (on[r]) gl_lds16(base + goff[r], dst + loff[r]);
        }
      }

      // ---- H-window accumulate from current buffer ----
      float hsI[8], hsJ[8], hsII[8], hsJJ[8], hsIJ[8];
      #pragma unroll
      for (int c = 0; c < 8; ++c) {
        hsI[c] = 0.f; hsJ[c] = 0.f; hsII[c] = 0.f; hsJJ[c] = 0.f; hsIJ[c] = 0.f;
      }
      if (s >= 0 && s < Dd) {
        const float* bufc = &tile[t & 1][0];
        #pragma unroll
        for (int dh = 0; dh < 5; ++dh) {
          const int rrow = ty + dh;            // rows ty..ty+4 <-> hh = hbase+ty-2+dh
          const int hh = hbase + rrow - 2;
          if (hh >= 0 && hh < Hd) {            // skip clamped-duplicate halo rows
            const float* pa = bufc + rrow * TROW + 4 * tx;  // 16B-aligned
            const float* pb = pa + ROWS * TROW;             // J array
            float a[8], b[8];
            ((float4*)a)[0] = ((const float4*)pa)[0];
            ((float4*)a)[1] = ((const float4*)pa)[1];
            ((float4*)b)[0] = ((const float4*)pb)[0];
            ((float4*)b)[1] = ((const float4*)pb)[1];
            if (zl) { a[2]=a[0]; a[3]=a[1]; a[0]=0.f; a[1]=0.f;
                      b[2]=b[0]; b[3]=b[1]; b[0]=0.f; b[1]=0.f; }
            if (zr) { a[4]=a[6]; a[5]=a[7]; a[6]=0.f; a[7]=0.f;
                      b[4]=b[6]; b[5]=b[7]; b[6]=0.f; b[7]=0.f; }
            #pragma unroll
            for (int c = 0; c < 8; ++c) {
              const float x = a[c], y = b[c];  // col w0-2+c
              hsI[c]  += x;
              hsJ[c]  += y;
              hsII[c] = fmaf(x, x, hsII[c]);
              hsJJ[c] = fmaf(y, y, hsJJ[c]);
              hsIJ[c] = fmaf(x, y, hsIJ[c]);
            }
          }
        }
      }

      // ---- W-window sliding sums -> new ring slot; running D-sum update ----
      float nw[5][4];
      wslide(hsI,  nw[0]);
      wslide(hsJ,  nw[1]);
      wslide(hsII, nw[2]);
      wslide(hsJJ, nw[3]);
      wslide(hsIJ, nw[4]);
      #pragma unroll
      for (int c = 0; c < 5; ++c) {
        #pragma unroll
        for (int k = 0; k < 4; ++k) {
          Dsum[c][k] += nw[c][k] - ring[p][c][k];  // add entering, drop leaving
          ring[p][c][k] = nw[c][k];
        }
      }

      // ---- cc epilogue ----
      const int d = d_lo + t - 4;
      if (t >= 4 && d < Dd) {
        #pragma unroll
        for (int k = 0; k < 4; ++k) {
          const float SI = Dsum[0][k], SJ = Dsum[1][k];
          const float SII = Dsum[2][k], SJJ = Dsum[3][k], SIJ = Dsum[4][k];
          const float cross = SIJ - SI * SJ * INV_V;
          const float vI    = SII - SI * SI * INV_V;
          const float vJ    = SJJ - SJ * SJ * INV_V;
          acc += cross * cross / (vI * vJ + EPSf);
        }
      }

      __syncthreads();  // drains DMA for s+1; reads of current buffer done
    }
  }

  // ---- block reduction -> single atomic per block ----
  #pragma unroll
  for (int off = 32; off > 0; off >>= 1) acc += __shfl_xor(acc, off, 64);
  if ((tid & 63) == 0) red[tid >> 6] = acc;
  __syncthreads();
  if (tid == 0) {
    const float total = red[0] + red[1] + red[2] + red[3];
    atomicAdd(out, total * (-1.0f / 11796480.0f)); // -mean over 2*160*192*192
  }
}

extern "C" void kernel_launch(void* const* d_in, const int* in_sizes, int n_in,
                              void* d_out, int out_size, void* d_ws, size_t ws_size,
                              hipStream_t stream) {
  const float* I = (const float*)d_in[0];
  const float* J = (const float*)d_in[1];
  float* out = (float*)d_out;
  hipMemsetAsync(out, 0, sizeof(float), stream);
  dim3 grid(3, 12, 2 * NCHUNK); // W tiles * H tiles * (n x 27 d-chunks of 6)
  ncc_fused<<<grid, 256, 0, stream>>>(I, J, out);
}